// Round 21
// baseline (139.798 us; speedup 1.0000x reference)
//
#include <hip/hip_runtime.h>

typedef __attribute__((ext_vector_type(4))) float float4v;
typedef __attribute__((ext_vector_type(2))) float float2v;
typedef __attribute__((ext_vector_type(8))) short short8;
typedef __attribute__((ext_vector_type(4))) float f32x4;

#define NEGV (-1000000000.0f)

// B=64, L=2048, E=512, Q=256; M = 131072, K = 512, N = 512
#define MTOT (64 * 2048)

__device__ __forceinline__ unsigned short f2bf(float f) {
    unsigned int u = __float_as_uint(f);
    u += 0x7fffu + ((u >> 16) & 1u);   // RNE round to bf16
    return (unsigned short)(u >> 16);
}

// async global->LDS, 16B per lane; LDS dest = wave-uniform base + lane*16
__device__ __forceinline__ void gload_lds16(const void* g, void* l) {
    __builtin_amdgcn_global_load_lds(
        (__attribute__((address_space(1))) unsigned int*)(unsigned long long)(g),
        (__attribute__((address_space(3))) unsigned int*)(unsigned int)(unsigned long long)(l),
        16, 0, 0);
}

// Wt[e][c] = bf16(W1[c][e]) via LDS 32x32 tile transpose.
__global__ __launch_bounds__(256)
void prep_wt_kernel(const float* __restrict__ W1, unsigned short* __restrict__ Wt) {
    __shared__ float t[32][33];
    int bx = blockIdx.x & 15;    // c tile
    int by = blockIdx.x >> 4;    // e tile
    int tx = threadIdx.x & 31;
    int ty = threadIdx.x >> 5;   // 0..7
    #pragma unroll
    for (int i = 0; i < 4; ++i)
        t[ty + 8 * i][tx] = W1[(bx * 32 + ty + 8 * i) * 512 + by * 32 + tx];
    __syncthreads();
    #pragma unroll
    for (int i = 0; i < 4; ++i)
        Wt[(by * 32 + ty + 8 * i) * 512 + bx * 32 + tx] = f2bf(t[tx][ty + 8 * i]);
}

// qc[b][e] = b1[e] + sum_q query[b][q] * W1[512+q][e]; also zeroes ctxraw/S.
__global__ void prep_qc_kernel(const float* __restrict__ query, const float* __restrict__ W1,
                               const float* __restrict__ b1, float* __restrict__ qc,
                               float* __restrict__ ctxraw, float* __restrict__ S) {
    int b = blockIdx.x;
    int e = threadIdx.x;           // 256 threads -> cols e and e+256
    ctxraw[b * 512 + e] = 0.f;
    ctxraw[b * 512 + 256 + e] = 0.f;
    if (e == 0) S[b] = 0.f;
    float acc0 = b1[e];
    float acc1 = b1[e + 256];
    const float* w = W1 + 512 * 512;
    #pragma unroll 8
    for (int q = 0; q < 256; ++q) {
        float qv = query[b * 256 + q];
        acc0 += qv * w[q * 512 + e];
        acc1 += qv * w[q * 512 + e + 256];
    }
    qc[b * 512 + e] = acc0;
    qc[b * 512 + e + 256] = acc1;
}

// Fused gemm, 512 threads (8 waves), BM=64 x BN=512 (full N), BK=32.
// LDS = 4KB As (single) + 2x32KB Bs = 68KB -> TWO blocks/CU genuinely fit
// (R20's 2x16-wave/72KB config never co-scheduled: 2x16x64 VGPR = exactly
// the file, reserves overflow it). Two independent 8-wave blocks per CU:
// one block's per-step drain overlaps the sibling's compute (m114).
// A-loads issued 2 steps ahead (reg ring Pa/Pb) -> ~900cyc f32-load latency
// covered; counted waits vmcnt(5)/vmcnt(1), never an empty drain.
__global__ __launch_bounds__(512)
void gemm_fused_kernel(const float* __restrict__ A,             // encoded [M][512] f32
                       const unsigned short* __restrict__ Wt,   // [512 n][512 k] bf16
                       const float* __restrict__ qc,            // [64][512]
                       const float* __restrict__ v,             // [512]
                       const int* __restrict__ length,          // [64]
                       float* __restrict__ att,                 // [M] raw w out
                       float* __restrict__ ctxraw,              // [64][512] accum
                       float* __restrict__ S)                   // [64] sum accum
{
    int bm = blockIdx.x;           // 0..2047 row tile (64 rows)
    int b = bm >> 5;
    int len = length[b];
    int l0 = (bm & 31) * 64;
    if (l0 >= len) return;         // fully-masked tile

    __shared__ char smem[69632];   // 68KB -> 2 blocks/CU (136KB + slack)
    unsigned short* As = (unsigned short*)smem;            // 4 KB single
    unsigned short* Bs = (unsigned short*)(smem + 4096);   // 2 x 32 KB
    float (*lred)[8] = (float(*)[8])(smem + 4096);         // overlay Bs slot0
    float* wbuf = (float*)(smem + 4096 + 2048);            // overlay Bs slot0

    int tid = threadIdx.x;
    int lane = tid & 63;
    int w = tid >> 6;              // 0..7 ; wave tile 64 x 64 (wn = w)
    long row0 = (long)bm * 64;

    // --- A reg-staging: thread -> row r = tid>>3 (0..63), 16B eighth e8 ---
    int ar_r = tid >> 3;
    int ar_e = tid & 7;
    const char* gAr = (const char*)A + (row0 + ar_r) * 2048 + ar_e * 16;
    int awr = ar_r * 64 + ((ar_e * 8) ^ (((ar_r >> 1) & 3) << 4));

    // --- B staging: 4 insts/wave/step; inst i covers LDS [w*4096+i*1024,+1K) ---
    const char* gBsrc[4];
    int boffs[4];
    #pragma unroll
    for (int i = 0; i < 4; ++i) {
        int o = w * 4096 + i * 1024 + lane * 16;
        int r = o >> 6;
        boffs[i] = o;
        gBsrc[i] = (const char*)Wt + r * 1024 + ((o & 63) ^ (((r >> 1) & 3) << 4));
    }

    // --- fragment read byte offsets ---
    int aoff[4], boff[4];
    int kb = 16 * (lane >> 4);
    #pragma unroll
    for (int mi = 0; mi < 4; ++mi) {
        int ar = mi * 16 + (lane & 15);
        aoff[mi] = ar * 64 + (kb ^ (((ar >> 1) & 3) << 4));
    }
    #pragma unroll
    for (int ni = 0; ni < 4; ++ni) {
        int br = w * 64 + ni * 16 + (lane & 15);
        boff[ni] = br * 64 + (kb ^ (((br >> 1) & 3) << 4));
    }

    f32x4 acc[4][4] = {};
    float4v Pa, Pb;                // A reg ring: step parity 0 -> Pa, 1 -> Pb

#define ALOAD(t_, P_) do { P_ = *(const float4v*)(gAr + (t_) * 128); } while (0)

#define BISSUE(t_, sI) do {                                                  \
    char* lb_ = (char*)Bs + (sI) * 32768;                                    \
    gload_lds16(gBsrc[0] + (t_) * 64, lb_ + boffs[0]);                       \
    gload_lds16(gBsrc[1] + (t_) * 64, lb_ + boffs[1]);                       \
    gload_lds16(gBsrc[2] + (t_) * 64, lb_ + boffs[2]);                       \
    gload_lds16(gBsrc[3] + (t_) * 64, lb_ + boffs[3]);                       \
} while (0)

#define CVTW(P_) do {                                                        \
    union { unsigned int u[2]; unsigned long long ll; } pk_;                 \
    pk_.u[0] = (unsigned int)f2bf(P_[0]) | ((unsigned int)f2bf(P_[1]) << 16); \
    pk_.u[1] = (unsigned int)f2bf(P_[2]) | ((unsigned int)f2bf(P_[3]) << 16); \
    *(unsigned long long*)((char*)As + awr) = pk_.ll;                        \
} while (0)

#define KCOMP(sC) do {                                                       \
    const char* as_ = (const char*)As;                                       \
    const char* bs_ = (const char*)Bs + (sC) * 32768;                        \
    short8 af_[4];                                                           \
    _Pragma("unroll")                                                        \
    for (int mi = 0; mi < 4; ++mi) af_[mi] = *(const short8*)(as_ + aoff[mi]); \
    _Pragma("unroll")                                                        \
    for (int ni = 0; ni < 4; ++ni) {                                         \
        short8 bf_ = *(const short8*)(bs_ + boff[ni]);                       \
        _Pragma("unroll")                                                    \
        for (int mi = 0; mi < 4; ++mi)                                       \
            acc[mi][ni] = __builtin_amdgcn_mfma_f32_16x16x32_bf16(af_[mi], bf_, acc[mi][ni], 0, 0, 0); \
    }                                                                        \
} while (0)

// step t: [issue A(t+2) -> P(t&1)] [issue B(t+1)] KCOMP(t) ; barrier
// (As readers done) ; vmcnt(VM1): A(t+1) landed ; CVTW ; vmcnt(VM2):
// B(t+1) staged (A(t+2) may stay outstanding) ; barrier.
#define KITER(t, PI, PC, AISS, VM1, VM2) do {                                \
    if (AISS) ALOAD((t) + 2, PI);                                            \
    BISSUE((t) + 1, ((t) + 1) & 1);                                          \
    KCOMP((t) & 1);                                                          \
    asm volatile("" ::: "memory");                                           \
    __builtin_amdgcn_s_barrier();                                            \
    asm volatile("s_waitcnt vmcnt(" #VM1 ")" ::: "memory");                  \
    CVTW(PC);                                                                \
    asm volatile("s_waitcnt vmcnt(" #VM2 ") lgkmcnt(0)" ::: "memory");       \
    __builtin_amdgcn_s_barrier();                                            \
    asm volatile("" ::: "memory");                                           \
} while (0)

    // prologue: A(0)->Pa, A(1)->Pb, B(0)->slot0
    ALOAD(0, Pa);
    ALOAD(1, Pb);
    BISSUE(0, 0);
    asm volatile("s_waitcnt vmcnt(5)" ::: "memory");   // A(0) done
    CVTW(Pa);
    asm volatile("s_waitcnt vmcnt(1) lgkmcnt(0)" ::: "memory");  // B(0) done
    __builtin_amdgcn_s_barrier();
    asm volatile("" ::: "memory");

    KITER(0,  Pa, Pb, 1, 5, 1);
    KITER(1,  Pb, Pa, 1, 5, 1);
    KITER(2,  Pa, Pb, 1, 5, 1);
    KITER(3,  Pb, Pa, 1, 5, 1);
    KITER(4,  Pa, Pb, 1, 5, 1);
    KITER(5,  Pb, Pa, 1, 5, 1);
    KITER(6,  Pa, Pb, 1, 5, 1);
    KITER(7,  Pb, Pa, 1, 5, 1);
    KITER(8,  Pa, Pb, 1, 5, 1);
    KITER(9,  Pb, Pa, 1, 5, 1);
    KITER(10, Pa, Pb, 1, 5, 1);
    KITER(11, Pb, Pa, 1, 5, 1);
    KITER(12, Pa, Pb, 1, 5, 1);
    KITER(13, Pb, Pa, 1, 5, 1);
    KITER(14, Pa, Pb, 0, 4, 0);    // no A(16); A(15) done at vmcnt(4)
    KCOMP(1);                      // t = 15

    // epilogue: u = tanh(acc + qc), 64-col partial per wave, 16-lane reduce,
    // in-block reduce over 8 wn waves via lred (on Bs slot0, dead now).
    const float* qcb = qc + b * 512;
    float vcol[4], qcol[4];
    #pragma unroll
    for (int ni = 0; ni < 4; ++ni) {
        int c = w * 64 + ni * 16 + (lane & 15);
        vcol[ni] = v[c];
        qcol[ni] = qcb[c];
    }
    #pragma unroll
    for (int mi = 0; mi < 4; ++mi) {
        #pragma unroll
        for (int j2 = 0; j2 < 4; ++j2) {
            float s = 0.f;
            #pragma unroll
            for (int ni = 0; ni < 4; ++ni) {
                float xx = acc[mi][ni][j2] + qcol[ni];
                float e2 = __expf(2.0f * xx);
                float tt = 1.0f - 2.0f * __builtin_amdgcn_rcpf(e2 + 1.0f);
                s += tt * vcol[ni];
            }
            s += __shfl_xor(s, 1);
            s += __shfl_xor(s, 2);
            s += __shfl_xor(s, 4);
            s += __shfl_xor(s, 8);
            if ((lane & 15) == 0)
                lred[mi * 16 + 4 * (lane >> 4) + j2][w] = s;
        }
    }
    __syncthreads();

    // fused: wf = exp(logit) (0 beyond length), raw wf -> att, sum -> S[b]
    if (tid < 64) {
        float lg = 0.f;
        #pragma unroll
        for (int q = 0; q < 8; ++q) lg += lred[tid][q];
        float wf = (l0 + tid < len) ? __expf(lg) : 0.f;
        att[row0 + tid] = wf;
        wbuf[tid] = wf;
        float s = wf;
        #pragma unroll
        for (int m = 32; m; m >>= 1) s += __shfl_xor(s, m);
        if (tid == 0) atomicAdd(&S[b], s);
    }
    __syncthreads();

    // fused ctx: thread covers col e = tid, all 64 rows (L2-hot A tile)
    {
        const float* encb = A + row0 * 512 + tid;
        float c = 0.f;
        #pragma unroll 4
        for (int l = 0; l < 64; ++l)
            c += wbuf[l] * encb[l * 512];
        atomicAdd(&ctxraw[b * 512 + tid], c);
    }
}

// normalize: att[l] = (l<len) ? w[l]/S[b] : 0 ; ctx = ctxraw/S[b]
__global__ void norm_kernel(const float* __restrict__ S, const int* __restrict__ length,
                            const float* __restrict__ ctxraw,
                            float* __restrict__ att, float* __restrict__ ctx) {
    int b = blockIdx.x;
    int tid = threadIdx.x;     // 256
    float inv = 1.0f / S[b];
    ctx[b * 512 + tid] = ctxraw[b * 512 + tid] * inv;
    ctx[b * 512 + 256 + tid] = ctxraw[b * 512 + 256 + tid] * inv;
    int len = length[b];
    float* ab = att + b * 2048;
    #pragma unroll
    for (int i = 0; i < 8; ++i) {
        int l = tid + i * 256;
        float wv = ab[l];
        ab[l] = (l < len) ? wv * inv : 0.f;
    }
}

extern "C" void kernel_launch(void* const* d_in, const int* in_sizes, int n_in,
                              void* d_out, int out_size, void* d_ws, size_t ws_size,
                              hipStream_t stream) {
    const float* enc    = (const float*)d_in[0];   // [64,2048,512]
    const float* query  = (const float*)d_in[1];   // [64,256]
    const int*   length = (const int*)d_in[2];     // [64]
    const float* W1     = (const float*)d_in[3];   // [768,512]
    const float* b1     = (const float*)d_in[4];   // [512]
    const float* v      = (const float*)d_in[5];   // [512]

    float* out = (float*)d_out;
    float* ctx = out;                // [64,512]
    float* att = out + 64 * 512;     // [64,2048]

    char* ws = (char*)d_ws;
    float* qc          = (float*)ws;                               // 128KB
    unsigned short* Wt = (unsigned short*)(ws + 64 * 512 * 4);     // 512KB
    float* ctxraw      = (float*)(ws + 64 * 512 * 4 + 512 * 1024); // 128KB
    float* S           = (float*)(ws + 64 * 512 * 4 + 512 * 1024 + 64 * 512 * 4); // 256B

    prep_wt_kernel<<<256, 256, 0, stream>>>(W1, Wt);
    prep_qc_kernel<<<64, 256, 0, stream>>>(query, W1, b1, qc, ctxraw, S);

    gemm_fused_kernel<<<2048, 512, 0, stream>>>(enc, Wt, qc, v, length, att, ctxraw, S);

    norm_kernel<<<64, 256, 0, stream>>>(S, length, ctxraw, att, ctx);
}

// Round 22
// 134.803 us; speedup vs baseline: 1.0371x; 1.0371x over previous
//
#include <hip/hip_runtime.h>

typedef __attribute__((ext_vector_type(4))) float float4v;
typedef __attribute__((ext_vector_type(2))) float float2v;
typedef __attribute__((ext_vector_type(8))) short short8;
typedef __attribute__((ext_vector_type(4))) float f32x4;

#define NEGV (-1000000000.0f)

// B=64, L=2048, E=512, Q=256; M = 131072, K = 512, N = 512
#define MTOT (64 * 2048)

__device__ __forceinline__ unsigned short f2bf(float f) {
    unsigned int u = __float_as_uint(f);
    u += 0x7fffu + ((u >> 16) & 1u);   // RNE round to bf16
    return (unsigned short)(u >> 16);
}

// async global->LDS, 16B per lane; LDS dest = wave-uniform base + lane*16
__device__ __forceinline__ void gload_lds16(const void* g, void* l) {
    __builtin_amdgcn_global_load_lds(
        (__attribute__((address_space(1))) unsigned int*)(unsigned long long)(g),
        (__attribute__((address_space(3))) unsigned int*)(unsigned int)(unsigned long long)(l),
        16, 0, 0);
}

// init: qc[b][e] = b1[e] (prep_qc atomicAdds onto it), ctxraw = 0, S = 0
__global__ __launch_bounds__(256)
void init_kernel(const float* __restrict__ b1, float* __restrict__ qc,
                 float* __restrict__ ctxraw, float* __restrict__ S) {
    int i = blockIdx.x * 256 + threadIdx.x;    // 0..65535
    if (i < 32768) {
        qc[i] = b1[i & 511];
    } else {
        ctxraw[i - 32768] = 0.f;
    }
    if (i < 64) S[i] = 0.f;
}

// Wt[e][c] = bf16(W1[c][e]) via LDS 32x32 tile transpose.
__global__ __launch_bounds__(256)
void prep_wt_kernel(const float* __restrict__ W1, unsigned short* __restrict__ Wt) {
    __shared__ float t[32][33];
    int bx = blockIdx.x & 15;    // c tile
    int by = blockIdx.x >> 4;    // e tile
    int tx = threadIdx.x & 31;
    int ty = threadIdx.x >> 5;   // 0..7
    #pragma unroll
    for (int i = 0; i < 4; ++i)
        t[ty + 8 * i][tx] = W1[(bx * 32 + ty + 8 * i) * 512 + by * 32 + tx];
    __syncthreads();
    #pragma unroll
    for (int i = 0; i < 4; ++i)
        Wt[(by * 32 + ty + 8 * i) * 512 + bx * 32 + tx] = f2bf(t[tx][ty + 8 * i]);
}

// qc[b][e] += sum over this block's 64-q quarter of query[b][q]*W1[512+q][e]
// 256 blocks (4 per batch) instead of 64 -> full CU coverage.
__global__ __launch_bounds__(256)
void prep_qc_kernel(const float* __restrict__ query, const float* __restrict__ W1,
                    float* __restrict__ qc) {
    int blk = blockIdx.x;          // 0..255
    int b = blk >> 2;
    int q0 = (blk & 3) * 64;
    int e = threadIdx.x;
    float acc0 = 0.f, acc1 = 0.f;
    const float* w = W1 + (512 + q0) * 512;
    const float* qv = query + b * 256 + q0;
    #pragma unroll 8
    for (int q = 0; q < 64; ++q) {
        float x = qv[q];
        acc0 += x * w[q * 512 + e];
        acc1 += x * w[q * 512 + e + 256];
    }
    atomicAdd(&qc[b * 512 + e], acc0);
    atomicAdd(&qc[b * 512 + e + 256], acc1);
}

// R17's fused gemm (BM=128 x BN=512, BK=32, 16 waves) with DEEP prefetch:
// 4-slot B ring (B(t+1) issued 2.5 steps before use -> L2-miss latency from
// the A-stream evicting Wt is fully covered), A loads 2 steps ahead (Pa/Pb).
// Single counted vmcnt(5) per step retires A(t+1)+B(t+1); never drained
// mid-loop. LDS 136KB (1 block/CU). Fused epilogue (exp/S/ctx) unchanged.
__global__ __launch_bounds__(1024)
void gemm_fused_kernel(const float* __restrict__ A,             // encoded [M][512] f32
                       const unsigned short* __restrict__ Wt,   // [512 n][512 k] bf16
                       const float* __restrict__ qc,            // [64][512]
                       const float* __restrict__ v,             // [512]
                       const int* __restrict__ length,          // [64]
                       float* __restrict__ att,                 // [M] raw w out
                       float* __restrict__ ctxraw,              // [64][512] accum
                       float* __restrict__ S)                   // [64] sum accum
{
    int bm = blockIdx.x;           // 0..1023 row tile
    int b = bm >> 4;
    int len = length[b];
    int l0 = (bm & 15) * 128;
    if (l0 >= len) return;         // fully-masked tile

    __shared__ char smem[139264];  // 8KB As + 4x32KB Bs = 136KB (pad to 136K)
    unsigned short* As = (unsigned short*)smem;            // 8 KB single
    unsigned short* Bs = (unsigned short*)(smem + 8192);   // 4 x 32 KB ring
    float (*lred)[8] = (float(*)[8])(smem + 8192);         // overlay Bs slot0
    float* wbuf = (float*)(smem + 8192 + 4096);            // overlay Bs slot0

    int tid = threadIdx.x;
    int lane = tid & 63;
    int w = tid >> 6;              // 0..15
    int wm = w >> 3, wn = w & 7;   // 2 x 8 wave grid; wave tile 64x64
    long row0 = (long)bm * 128;

    // --- A reg-staging: thread -> row r = tid>>3, k-eighth e8 = tid&7 (16B) ---
    int ar_r = tid >> 3;
    int ar_e = tid & 7;
    const char* gAr = (const char*)A + (row0 + ar_r) * 2048 + ar_e * 16;
    int awr = ar_r * 64 + ((ar_e * 8) ^ (((ar_r >> 1) & 3) << 4));

    // --- B staging: 2 insts/wave/step; linear LDS dest, pre-swizzled src ---
    int offw = w * 2048 + lane * 16;             // this wave's 2KB of 32KB slot
    const char* gB0;
    const char* gB1;
    {
        int o = offw;
        int r = o >> 6;
        gB0 = (const char*)Wt + r * 1024 + ((o & 63) ^ (((r >> 1) & 3) << 4));
        o = offw + 1024;
        r = o >> 6;
        gB1 = (const char*)Wt + r * 1024 + ((o & 63) ^ (((r >> 1) & 3) << 4));
    }

    // --- fragment read byte offsets ---
    int aoff[4], boff[4];
    int kb = 16 * (lane >> 4);
    #pragma unroll
    for (int mi = 0; mi < 4; ++mi) {
        int ar = wm * 64 + (lane & 15) + mi * 16;
        aoff[mi] = ar * 64 + (kb ^ (((ar >> 1) & 3) << 4));
    }
    #pragma unroll
    for (int ni = 0; ni < 4; ++ni) {
        int br = wn * 64 + (lane & 15) + ni * 16;
        boff[ni] = br * 64 + (kb ^ (((br >> 1) & 3) << 4));
    }

    f32x4 acc[4][4] = {};
    float4v Pa, Pb;                // A ring, 2 steps deep

#define ALOAD(t_, P_) do { P_ = *(const float4v*)(gAr + (t_) * 128); } while (0)

#define BISSUE(t_, sI) do {                                                  \
    char* lb_ = (char*)Bs + (sI) * 32768 + offw;                             \
    gload_lds16(gB0 + (t_) * 64, lb_);                                       \
    gload_lds16(gB1 + (t_) * 64, lb_ + 1024);                                \
} while (0)

#define CVTW(P_) do {                                                        \
    union { unsigned int u[2]; unsigned long long ll; } pk_;                 \
    pk_.u[0] = (unsigned int)f2bf(P_[0]) | ((unsigned int)f2bf(P_[1]) << 16); \
    pk_.u[1] = (unsigned int)f2bf(P_[2]) | ((unsigned int)f2bf(P_[3]) << 16); \
    *(unsigned long long*)((char*)As + awr) = pk_.ll;                        \
} while (0)

#define KCOMP(sC) do {                                                       \
    const char* as_ = (const char*)As;                                       \
    const char* bs_ = (const char*)Bs + (sC) * 32768;                        \
    short8 af_[4];                                                           \
    _Pragma("unroll")                                                        \
    for (int mi = 0; mi < 4; ++mi) af_[mi] = *(const short8*)(as_ + aoff[mi]); \
    _Pragma("unroll")                                                        \
    for (int ni = 0; ni < 4; ++ni) {                                         \
        short8 bf_ = *(const short8*)(bs_ + boff[ni]);                       \
        _Pragma("unroll")                                                    \
        for (int mi = 0; mi < 4; ++mi)                                       \
            acc[mi][ni] = __builtin_amdgcn_mfma_f32_16x16x32_bf16(af_[mi], bf_, acc[mi][ni], 0, 0, 0); \
    }                                                                        \
} while (0)

// step t: issue A(t+2), B(t+3); KCOMP(t); barrier (As readers done);
// vmcnt(VM): A(t+1) AND B(t+1) retired (both issued >=1.5 steps ago);
// CVTW(A(t+1)); lgkmcnt(0); barrier.
#define KITER(t, PI, PC, AISS, BISS, VM) do {                                \
    if (AISS) ALOAD((t) + 2, PI);                                            \
    if (BISS) BISSUE((t) + 3, ((t) + 3) & 3);                                \
    KCOMP((t) & 3);                                                          \
    asm volatile("" ::: "memory");                                           \
    __builtin_amdgcn_s_barrier();                                            \
    asm volatile("s_waitcnt vmcnt(" #VM ")" ::: "memory");                   \
    CVTW(PC);                                                                \
    asm volatile("s_waitcnt lgkmcnt(0)" ::: "memory");                       \
    __builtin_amdgcn_s_barrier();                                            \
    asm volatile("" ::: "memory");                                           \
} while (0)

    // prologue: A(0),A(1) in regs; B(0),B(1),B(2) in flight
    ALOAD(0, Pa);
    ALOAD(1, Pb);
    BISSUE(0, 0);
    BISSUE(1, 1);
    BISSUE(2, 2);
    asm volatile("s_waitcnt vmcnt(4)" ::: "memory");   // A(0),A(1),B(0) done
    CVTW(Pa);
    asm volatile("s_waitcnt lgkmcnt(0)" ::: "memory");
    __builtin_amdgcn_s_barrier();
    asm volatile("" ::: "memory");

    KITER(0,  Pa, Pb, 1, 1, 5);
    KITER(1,  Pb, Pa, 1, 1, 5);
    KITER(2,  Pa, Pb, 1, 1, 5);
    KITER(3,  Pb, Pa, 1, 1, 5);
    KITER(4,  Pa, Pb, 1, 1, 5);
    KITER(5,  Pb, Pa, 1, 1, 5);
    KITER(6,  Pa, Pb, 1, 1, 5);
    KITER(7,  Pb, Pa, 1, 1, 5);
    KITER(8,  Pa, Pb, 1, 1, 5);
    KITER(9,  Pb, Pa, 1, 1, 5);
    KITER(10, Pa, Pb, 1, 1, 5);
    KITER(11, Pb, Pa, 1, 1, 5);
    KITER(12, Pa, Pb, 1, 1, 5);
    KITER(13, Pb, Pa, 1, 0, 3);    // last ALOAD (A15); B ring full
    KITER(14, Pa, Pb, 0, 0, 0);    // drain: A(15)+B(15) retired
    KCOMP(3);                      // t = 15

    // epilogue: u = tanh(acc + qc), per-wave 64-col partial via 16-lane
    // reduce, then in-block reduce over 8 wn waves (lred on Bs slot0 —
    // last slot-0 reader was KCOMP(12); steps 13-15 touch slots 1-3 only).
    const float* qcb = qc + b * 512;
    float vcol[4], qcol[4];
    #pragma unroll
    for (int ni = 0; ni < 4; ++ni) {
        int c = wn * 64 + ni * 16 + (lane & 15);
        vcol[ni] = v[c];
        qcol[ni] = qcb[c];
    }
    #pragma unroll
    for (int mi = 0; mi < 4; ++mi) {
        #pragma unroll
        for (int j2 = 0; j2 < 4; ++j2) {
            float s = 0.f;
            #pragma unroll
            for (int ni = 0; ni < 4; ++ni) {
                float xx = acc[mi][ni][j2] + qcol[ni];
                float e2 = __expf(2.0f * xx);
                float tt = 1.0f - 2.0f * __builtin_amdgcn_rcpf(e2 + 1.0f);
                s += tt * vcol[ni];
            }
            s += __shfl_xor(s, 1);
            s += __shfl_xor(s, 2);
            s += __shfl_xor(s, 4);
            s += __shfl_xor(s, 8);
            if ((lane & 15) == 0)
                lred[wm * 64 + mi * 16 + 4 * (lane >> 4) + j2][wn] = s;
        }
    }
    __syncthreads();

    // fused: w = exp(logit) (0 beyond length), raw w -> att, sum -> S[b]
    if (tid < 128) {
        float lg = 0.f;
        #pragma unroll
        for (int q = 0; q < 8; ++q) lg += lred[tid][q];
        float wf = (l0 + tid < len) ? __expf(lg) : 0.f;
        att[row0 + tid] = wf;
        wbuf[tid] = wf;
        float s = wf;
        #pragma unroll
        for (int m = 32; m; m >>= 1) s += __shfl_xor(s, m);
        if ((tid & 63) == 0) atomicAdd(&S[b], s);
    }
    __syncthreads();

    // fused ctx: thread covers e = tid&511, l-half = tid>>9 (L2-hot A tile)
    {
        int e = tid & 511;
        int lh = tid >> 9;                 // 0 or 1
        const float* encb = A + (row0 + lh * 64) * 512 + e;
        const float* wb = &wbuf[lh * 64];
        float c = 0.f;
        #pragma unroll 4
        for (int l = 0; l < 64; ++l)
            c += wb[l] * encb[l * 512];
        atomicAdd(&ctxraw[b * 512 + e], c);
    }
}

// normalize: att[l] = (l<len) ? w[l]/S[b] : 0 ; ctx = ctxraw/S[b]
__global__ void norm_kernel(const float* __restrict__ S, const int* __restrict__ length,
                            const float* __restrict__ ctxraw,
                            float* __restrict__ att, float* __restrict__ ctx) {
    int b = blockIdx.x;
    int tid = threadIdx.x;     // 256
    float inv = 1.0f / S[b];
    ctx[b * 512 + tid] = ctxraw[b * 512 + tid] * inv;
    ctx[b * 512 + 256 + tid] = ctxraw[b * 512 + 256 + tid] * inv;
    int len = length[b];
    float* ab = att + b * 2048;
    #pragma unroll
    for (int i = 0; i < 8; ++i) {
        int l = tid + i * 256;
        float wv = ab[l];
        ab[l] = (l < len) ? wv * inv : 0.f;
    }
}

extern "C" void kernel_launch(void* const* d_in, const int* in_sizes, int n_in,
                              void* d_out, int out_size, void* d_ws, size_t ws_size,
                              hipStream_t stream) {
    const float* enc    = (const float*)d_in[0];   // [64,2048,512]
    const float* query  = (const float*)d_in[1];   // [64,256]
    const int*   length = (const int*)d_in[2];     // [64]
    const float* W1     = (const float*)d_in[3];   // [768,512]
    const float* b1     = (const float*)d_in[4];   // [512]
    const float* v      = (const float*)d_in[5];   // [512]

    float* out = (float*)d_out;
    float* ctx = out;                // [64,512]
    float* att = out + 64 * 512;     // [64,2048]

    char* ws = (char*)d_ws;
    float* qc          = (float*)ws;                               // 128KB
    unsigned short* Wt = (unsigned short*)(ws + 64 * 512 * 4);     // 512KB
    float* ctxraw      = (float*)(ws + 64 * 512 * 4 + 512 * 1024); // 128KB
    float* S           = (float*)(ws + 64 * 512 * 4 + 512 * 1024 + 64 * 512 * 4); // 256B

    init_kernel<<<256, 256, 0, stream>>>(b1, qc, ctxraw, S);
    prep_wt_kernel<<<256, 256, 0, stream>>>(W1, Wt);
    prep_qc_kernel<<<256, 256, 0, stream>>>(query, W1, qc);

    gemm_fused_kernel<<<1024, 1024, 0, stream>>>(enc, Wt, qc, v, length, att, ctxraw, S);

    norm_kernel<<<64, 256, 0, stream>>>(S, length, ctxraw, att, ctx);
}

// Round 23
// 126.020 us; speedup vs baseline: 1.1093x; 1.0697x over previous
//
#include <hip/hip_runtime.h>

typedef __attribute__((ext_vector_type(4))) float float4v;
typedef __attribute__((ext_vector_type(2))) float float2v;
typedef __attribute__((ext_vector_type(8))) short short8;
typedef __attribute__((ext_vector_type(4))) float f32x4;

#define NEGV (-1000000000.0f)

// B=64, L=2048, E=512, Q=256; M = 131072, K = 512, N = 512
#define MTOT (64 * 2048)

__device__ __forceinline__ unsigned short f2bf(float f) {
    unsigned int u = __float_as_uint(f);
    u += 0x7fffu + ((u >> 16) & 1u);   // RNE round to bf16
    return (unsigned short)(u >> 16);
}

// async global->LDS, 16B per lane; LDS dest = wave-uniform base + lane*16
__device__ __forceinline__ void gload_lds16(const void* g, void* l) {
    __builtin_amdgcn_global_load_lds(
        (__attribute__((address_space(1))) unsigned int*)(unsigned long long)(g),
        (__attribute__((address_space(3))) unsigned int*)(unsigned int)(unsigned long long)(l),
        16, 0, 0);
}

// init: qc[b][e] = b1[e] (prep_qc atomicAdds onto it), ctxraw = 0, S = 0
__global__ __launch_bounds__(256)
void init_kernel(const float* __restrict__ b1, float* __restrict__ qc,
                 float* __restrict__ ctxraw, float* __restrict__ S) {
    int i = blockIdx.x * 256 + threadIdx.x;    // 0..65535
    if (i < 32768) {
        qc[i] = b1[i & 511];
    } else {
        ctxraw[i - 32768] = 0.f;
    }
    if (i < 64) S[i] = 0.f;
}

// Wt[e][c] = bf16(W1[c][e]) via LDS 32x32 tile transpose.
__global__ __launch_bounds__(256)
void prep_wt_kernel(const float* __restrict__ W1, unsigned short* __restrict__ Wt) {
    __shared__ float t[32][33];
    int bx = blockIdx.x & 15;    // c tile
    int by = blockIdx.x >> 4;    // e tile
    int tx = threadIdx.x & 31;
    int ty = threadIdx.x >> 5;   // 0..7
    #pragma unroll
    for (int i = 0; i < 4; ++i)
        t[ty + 8 * i][tx] = W1[(bx * 32 + ty + 8 * i) * 512 + by * 32 + tx];
    __syncthreads();
    #pragma unroll
    for (int i = 0; i < 4; ++i)
        Wt[(by * 32 + ty + 8 * i) * 512 + bx * 32 + tx] = f2bf(t[tx][ty + 8 * i]);
}

// qc[b][e] += this block's 64-q quarter of query[b][q]*W1[512+q][e]
__global__ __launch_bounds__(256)
void prep_qc_kernel(const float* __restrict__ query, const float* __restrict__ W1,
                    float* __restrict__ qc) {
    int blk = blockIdx.x;          // 0..255
    int b = blk >> 2;
    int q0 = (blk & 3) * 64;
    int e = threadIdx.x;
    float acc0 = 0.f, acc1 = 0.f;
    const float* w = W1 + (512 + q0) * 512;
    const float* qv = query + b * 256 + q0;
    #pragma unroll 8
    for (int q = 0; q < 64; ++q) {
        float x = qv[q];
        acc0 += x * w[q * 512 + e];
        acc1 += x * w[q * 512 + e + 256];
    }
    atomicAdd(&qc[b * 512 + e], acc0);
    atomicAdd(&qc[b * 512 + e + 256], acc1);
}

// R22's fused gemm with TWO K-steps per barrier phase (8 phases, not 16):
// per phase issue B(2p+2),B(2p+3) (4-slot ring) + A(2p+4),A(2p+5) (4-reg
// ring), 32 MFMA/wave between barriers, single counted vmcnt(2) mid-phase,
// dual CVTW into 2-slot As. Halves the barrier/reconvergence overhead that
// the counters say dominates (all pipes <14% busy, latency fully covered).
__global__ __launch_bounds__(1024)
void gemm_fused_kernel(const float* __restrict__ A,             // encoded [M][512] f32
                       const unsigned short* __restrict__ Wt,   // [512 n][512 k] bf16
                       const float* __restrict__ qc,            // [64][512]
                       const float* __restrict__ v,             // [512]
                       const int* __restrict__ length,          // [64]
                       float* __restrict__ att,                 // [M] raw w out
                       float* __restrict__ ctxraw,              // [64][512] accum
                       float* __restrict__ S)                   // [64] sum accum
{
    int bm = blockIdx.x;           // 0..1023 row tile
    int b = bm >> 4;
    int len = length[b];
    int l0 = (bm & 15) * 128;
    if (l0 >= len) return;         // fully-masked tile

    __shared__ char smem[147456];  // 16KB As(2 slots) + 128KB Bs(4 slots)
    unsigned short* As = (unsigned short*)smem;            // 2 x 8 KB
    unsigned short* Bs = (unsigned short*)(smem + 16384);  // 4 x 32 KB ring
    float (*lred)[8] = (float(*)[8])(smem + 16384);        // overlay Bs slot0
    float* wbuf = (float*)(smem + 16384 + 4096);           // overlay Bs slot0

    int tid = threadIdx.x;
    int lane = tid & 63;
    int w = tid >> 6;              // 0..15
    int wm = w >> 3, wn = w & 7;   // 2 x 8 wave grid; wave tile 64x64
    long row0 = (long)bm * 128;

    // --- A reg-staging: thread -> row r = tid>>3, k-eighth e8 = tid&7 (16B) ---
    int ar_r = tid >> 3;
    int ar_e = tid & 7;
    const char* gAr = (const char*)A + (row0 + ar_r) * 2048 + ar_e * 16;
    int awr = ar_r * 64 + ((ar_e * 8) ^ (((ar_r >> 1) & 3) << 4));

    // --- B staging: 2 insts/wave/step; linear LDS dest, pre-swizzled src ---
    int offw = w * 2048 + lane * 16;             // this wave's 2KB of 32KB slot
    const char* gB0;
    const char* gB1;
    {
        int o = offw;
        int r = o >> 6;
        gB0 = (const char*)Wt + r * 1024 + ((o & 63) ^ (((r >> 1) & 3) << 4));
        o = offw + 1024;
        r = o >> 6;
        gB1 = (const char*)Wt + r * 1024 + ((o & 63) ^ (((r >> 1) & 3) << 4));
    }

    // --- fragment read byte offsets ---
    int aoff[4], boff[4];
    int kb = 16 * (lane >> 4);
    #pragma unroll
    for (int mi = 0; mi < 4; ++mi) {
        int ar = wm * 64 + (lane & 15) + mi * 16;
        aoff[mi] = ar * 64 + (kb ^ (((ar >> 1) & 3) << 4));
    }
    #pragma unroll
    for (int ni = 0; ni < 4; ++ni) {
        int br = wn * 64 + (lane & 15) + ni * 16;
        boff[ni] = br * 64 + (kb ^ (((br >> 1) & 3) << 4));
    }

    f32x4 acc[4][4] = {};
    float4v Pa, Pb, Pc, Pd;        // A ring, 4 steps deep

#define ALOAD(t_, P_) do { P_ = *(const float4v*)(gAr + (t_) * 128); } while (0)

#define BISSUE(t_, sI) do {                                                  \
    char* lb_ = (char*)Bs + (sI) * 32768 + offw;                             \
    gload_lds16(gB0 + (t_) * 64, lb_);                                       \
    gload_lds16(gB1 + (t_) * 64, lb_ + 1024);                                \
} while (0)

#define CVTW(P_, sW) do {                                                    \
    union { unsigned int u[2]; unsigned long long ll; } pk_;                 \
    pk_.u[0] = (unsigned int)f2bf(P_[0]) | ((unsigned int)f2bf(P_[1]) << 16); \
    pk_.u[1] = (unsigned int)f2bf(P_[2]) | ((unsigned int)f2bf(P_[3]) << 16); \
    *(unsigned long long*)((char*)As + (sW) * 8192 + awr) = pk_.ll;          \
} while (0)

#define KCOMP(sA, sB) do {                                                   \
    const char* as_ = (const char*)As + (sA) * 8192;                         \
    const char* bs_ = (const char*)Bs + (sB) * 32768;                        \
    short8 af_[4];                                                           \
    _Pragma("unroll")                                                        \
    for (int mi = 0; mi < 4; ++mi) af_[mi] = *(const short8*)(as_ + aoff[mi]); \
    _Pragma("unroll")                                                        \
    for (int ni = 0; ni < 4; ++ni) {                                         \
        short8 bf_ = *(const short8*)(bs_ + boff[ni]);                       \
        _Pragma("unroll")                                                    \
        for (int mi = 0; mi < 4; ++mi)                                       \
            acc[mi][ni] = __builtin_amdgcn_mfma_f32_16x16x32_bf16(af_[mi], bf_, acc[mi][ni], 0, 0, 0); \
    }                                                                        \
} while (0)

// phase p: steps 2p,2p+1. Issue B(2p+2),B(2p+3) then A(2p+4),A(2p+5);
// 2 KCOMPs; barrier (As/Bs readers done); vmcnt(VM) retires everything
// except the 2 new A loads; dual CVTW; lgkm; barrier.
#define PHASE(p, PI0, PI1, PC0, PC1, AISS, VM) do {                          \
    BISSUE(2*(p)+2, (2*(p)+2) & 3);                                          \
    BISSUE(2*(p)+3, (2*(p)+3) & 3);                                          \
    if (AISS) { ALOAD(2*(p)+4, PI0); ALOAD(2*(p)+5, PI1); }                  \
    KCOMP(0, (2*(p)) & 3);                                                   \
    KCOMP(1, (2*(p)+1) & 3);                                                 \
    asm volatile("" ::: "memory");                                           \
    __builtin_amdgcn_s_barrier();                                            \
    asm volatile("s_waitcnt vmcnt(" #VM ")" ::: "memory");                   \
    CVTW(PC0, 0);                                                            \
    CVTW(PC1, 1);                                                            \
    asm volatile("s_waitcnt lgkmcnt(0)" ::: "memory");                       \
    __builtin_amdgcn_s_barrier();                                            \
    asm volatile("" ::: "memory");                                           \
} while (0)

    // prologue: A(0..3) in regs, B(0),B(1) in flight; publish As slots 0,1
    ALOAD(0, Pa);
    ALOAD(1, Pb);
    BISSUE(0, 0);
    BISSUE(1, 1);
    ALOAD(2, Pc);
    ALOAD(3, Pd);
    asm volatile("s_waitcnt vmcnt(2)" ::: "memory");   // A0,A1,B0,B1 done
    CVTW(Pa, 0);
    CVTW(Pb, 1);
    asm volatile("s_waitcnt lgkmcnt(0)" ::: "memory");
    __builtin_amdgcn_s_barrier();
    asm volatile("" ::: "memory");

    PHASE(0, Pa, Pb, Pc, Pd, 1, 2);
    PHASE(1, Pc, Pd, Pa, Pb, 1, 2);
    PHASE(2, Pa, Pb, Pc, Pd, 1, 2);
    PHASE(3, Pc, Pd, Pa, Pb, 1, 2);
    PHASE(4, Pa, Pb, Pc, Pd, 1, 2);
    PHASE(5, Pc, Pd, Pa, Pb, 1, 2);
    PHASE(6, Pa, Pb, Pc, Pd, 0, 0);    // no new A; drain to 0
    KCOMP(0, 2);                       // step 14
    KCOMP(1, 3);                       // step 15

    // epilogue: u = tanh(acc + qc), per-wave 64-col partial via 16-lane
    // reduce, then in-block reduce over 8 wn waves (lred on Bs slot0 —
    // last slot-0 read was step 12 in phase 6; final KCOMPs touch slots 2,3).
    const float* qcb = qc + b * 512;
    float vcol[4], qcol[4];
    #pragma unroll
    for (int ni = 0; ni < 4; ++ni) {
        int c = wn * 64 + ni * 16 + (lane & 15);
        vcol[ni] = v[c];
        qcol[ni] = qcb[c];
    }
    #pragma unroll
    for (int mi = 0; mi < 4; ++mi) {
        #pragma unroll
        for (int j2 = 0; j2 < 4; ++j2) {
            float s = 0.f;
            #pragma unroll
            for (int ni = 0; ni < 4; ++ni) {
                float xx = acc[mi][ni][j2] + qcol[ni];
                float e2 = __expf(2.0f * xx);
                float tt = 1.0f - 2.0f * __builtin_amdgcn_rcpf(e2 + 1.0f);
                s += tt * vcol[ni];
            }
            s += __shfl_xor(s, 1);
            s += __shfl_xor(s, 2);
            s += __shfl_xor(s, 4);
            s += __shfl_xor(s, 8);
            if ((lane & 15) == 0)
                lred[wm * 64 + mi * 16 + 4 * (lane >> 4) + j2][wn] = s;
        }
    }
    __syncthreads();

    // fused: w = exp(logit) (0 beyond length), raw w -> att, sum -> S[b]
    if (tid < 128) {
        float lg = 0.f;
        #pragma unroll
        for (int q = 0; q < 8; ++q) lg += lred[tid][q];
        float wf = (l0 + tid < len) ? __expf(lg) : 0.f;
        att[row0 + tid] = wf;
        wbuf[tid] = wf;
        float s = wf;
        #pragma unroll
        for (int m = 32; m; m >>= 1) s += __shfl_xor(s, m);
        if ((tid & 63) == 0) atomicAdd(&S[b], s);
    }
    __syncthreads();

    // fused ctx: thread covers e = tid&511, l-half = tid>>9 (L2-hot A tile)
    {
        int e = tid & 511;
        int lh = tid >> 9;                 // 0 or 1
        const float* encb = A + (row0 + lh * 64) * 512 + e;
        const float* wb = &wbuf[lh * 64];
        float c = 0.f;
        #pragma unroll 4
        for (int l = 0; l < 64; ++l)
            c += wb[l] * encb[l * 512];
        atomicAdd(&ctxraw[b * 512 + e], c);
    }
}

// normalize: att[l] = (l<len) ? w[l]/S[b] : 0 ; ctx = ctxraw/S[b]
__global__ void norm_kernel(const float* __restrict__ S, const int* __restrict__ length,
                            const float* __restrict__ ctxraw,
                            float* __restrict__ att, float* __restrict__ ctx) {
    int b = blockIdx.x;
    int tid = threadIdx.x;     // 256
    float inv = 1.0f / S[b];
    ctx[b * 512 + tid] = ctxraw[b * 512 + tid] * inv;
    ctx[b * 512 + 256 + tid] = ctxraw[b * 512 + 256 + tid] * inv;
    int len = length[b];
    float* ab = att + b * 2048;
    #pragma unroll
    for (int i = 0; i < 8; ++i) {
        int l = tid + i * 256;
        float wv = ab[l];
        ab[l] = (l < len) ? wv * inv : 0.f;
    }
}

extern "C" void kernel_launch(void* const* d_in, const int* in_sizes, int n_in,
                              void* d_out, int out_size, void* d_ws, size_t ws_size,
                              hipStream_t stream) {
    const float* enc    = (const float*)d_in[0];   // [64,2048,512]
    const float* query  = (const float*)d_in[1];   // [64,256]
    const int*   length = (const int*)d_in[2];     // [64]
    const float* W1     = (const float*)d_in[3];   // [768,512]
    const float* b1     = (const float*)d_in[4];   // [512]
    const float* v      = (const float*)d_in[5];   // [512]

    float* out = (float*)d_out;
    float* ctx = out;                // [64,512]
    float* att = out + 64 * 512;     // [64,2048]

    char* ws = (char*)d_ws;
    float* qc          = (float*)ws;                               // 128KB
    unsigned short* Wt = (unsigned short*)(ws + 64 * 512 * 4);     // 512KB
    float* ctxraw      = (float*)(ws + 64 * 512 * 4 + 512 * 1024); // 128KB
    float* S           = (float*)(ws + 64 * 512 * 4 + 512 * 1024 + 64 * 512 * 4); // 256B

    init_kernel<<<256, 256, 0, stream>>>(b1, qc, ctxraw, S);
    prep_wt_kernel<<<256, 256, 0, stream>>>(W1, Wt);
    prep_qc_kernel<<<256, 256, 0, stream>>>(query, W1, qc);

    gemm_fused_kernel<<<1024, 1024, 0, stream>>>(enc, Wt, qc, v, length, att, ctxraw, S);

    norm_kernel<<<64, 256, 0, stream>>>(S, length, ctxraw, att, ctx);
}